// Round 2
// baseline (25307.605 us; speedup 1.0000x reference)
//
#include <hip/hip_runtime.h>
#include <stdint.h>

#define N_     4096
#define B_     64
#define NB_    (N_*B_)      // 262144
#define T_     128
#define DT_    0.01f
#define VMEAN_ (-75.0f)
#define VSTD_  115.0f

typedef short bf16x8 __attribute__((ext_vector_type(8)));
typedef float f32x4  __attribute__((ext_vector_type(4)));

static __device__ __forceinline__ uint16_t f2bf(float f) {
  union { float f; uint32_t u; } v; v.f = f;
  uint32_t u = v.u;
  return (uint16_t)((u + 0x7FFFu + ((u >> 16) & 1u)) >> 16);  // RNE
}

static __device__ __forceinline__ float fast_tanh(float x) {
  // tanh(x) = 1 - 2/(exp2(x*2/ln2)+1); saturates cleanly for |x| large
  float ex = __builtin_amdgcn_exp2f(x * 2.8853900817779268f);
  return 1.0f - 2.0f * __builtin_amdgcn_rcpf(ex + 1.0f);
}

static __device__ __forceinline__ f32x4 mfma16(bf16x8 a, bf16x8 b, f32x4 c) {
  return __builtin_amdgcn_mfma_f32_16x16x32_bf16(a, b, c, 0, 0, 0);
}

// ---------------- prep: transpose 128x128 W2 matrices to bf16 [j][k] ----------------
__global__ void k_prep_small(const float* __restrict__ fW2, const float* __restrict__ iW2,
                             uint16_t* __restrict__ W2fT, uint16_t* __restrict__ W2iT) {
  const float* src = (blockIdx.x == 0) ? fW2 : iW2;
  uint16_t* dst = (blockIdx.x == 0) ? W2fT : W2iT;
  int t = threadIdx.x;
  for (int e = 0; e < 64; ++e) {
    int idx = e * 256 + t;           // idx = j*128 + k
    int j = idx >> 7, k = idx & 127;
    dst[idx] = f2bf(src[k * 128 + j]);
  }
}

// ---------------- prep: A_pre = inv_pde @ mass (bf16 out, fp32 in) ----------------
__global__ __launch_bounds__(256) void k_prep_gemm(const float* __restrict__ Ipde,
                                                   const float* __restrict__ Mmat,
                                                   uint16_t* __restrict__ Apre) {
  __shared__ __align__(16) uint16_t Al[128 * 72];
  __shared__ __align__(16) uint16_t Bl[128 * 72];
  int t = threadIdx.x;
  int row0 = (blockIdx.x >> 5) * 128;
  int col0 = (blockIdx.x & 31) * 128;
  int w = t >> 6, l = t & 63;
  int wr = (w >> 1) * 64, wc = (w & 1) * 64;
  f32x4 acc[4][4];
  for (int i = 0; i < 4; ++i)
    for (int j = 0; j < 4; ++j) { f32x4 z = {0.f,0.f,0.f,0.f}; acc[i][j] = z; }
  for (int ch = 0; ch < 64; ++ch) {
    int k0 = ch * 64;
    __syncthreads();
    // A: Ipde[row0+r][k0+kk] -> Al[r][kk]  (convert fp32->bf16, pairs)
    for (int e = 0; e < 16; ++e) {
      int idx = e * 256 + t;
      int r = idx >> 5;
      int kp = (idx & 31) * 2;
      const float2 f2v = *(const float2*)(Ipde + (size_t)(row0 + r) * 4096 + k0 + kp);
      uint32_t pk = (uint32_t)f2bf(f2v.x) | ((uint32_t)f2bf(f2v.y) << 16);
      *(uint32_t*)&Al[r * 72 + kp] = pk;
    }
    // B transposed: Mmat[k0+kk][col0+jj] -> Bl[jj][kk]
    for (int e = 0; e < 32; ++e) {
      int idx = e * 256 + t;
      int kk = idx >> 7, jj = idx & 127;
      Bl[jj * 72 + kk] = f2bf(Mmat[(size_t)(k0 + kk) * 4096 + col0 + jj]);
    }
    __syncthreads();
    for (int ks = 0; ks < 2; ++ks) {
      bf16x8 af[4], bfv[4];
      for (int rt = 0; rt < 4; ++rt)
        af[rt] = *(const bf16x8*)&Al[(wr + rt * 16 + (l & 15)) * 72 + (l >> 4) * 8 + ks * 32];
      for (int ct = 0; ct < 4; ++ct)
        bfv[ct] = *(const bf16x8*)&Bl[(wc + ct * 16 + (l & 15)) * 72 + (l >> 4) * 8 + ks * 32];
      for (int rt = 0; rt < 4; ++rt)
        for (int ct = 0; ct < 4; ++ct)
          acc[rt][ct] = mfma16(af[rt], bfv[ct], acc[rt][ct]);
    }
  }
  for (int rt = 0; rt < 4; ++rt)
    for (int ct = 0; ct < 4; ++ct)
      for (int e = 0; e < 4; ++e) {
        int i = row0 + wr + rt * 16 + (l >> 4) * 4 + e;
        int j = col0 + wc + ct * 16 + (l & 15);
        Apre[(size_t)i * 4096 + j] = f2bf(acc[rt][ct][e]);
      }
}

// ---------------- per-step fused MLP kernel ----------------
__global__ __launch_bounds__(256) void k_mlp(
    const float* __restrict__ vsrc, int vparts,
    const float* __restrict__ ssrc, float* __restrict__ sdst,
    const float* __restrict__ Isrc,
    const uint16_t* __restrict__ W2fT, const uint16_t* __restrict__ W2iT,
    const float* __restrict__ fW1, const float* __restrict__ fb1,
    const float* __restrict__ fb2, const float* __restrict__ fW3, const float* __restrict__ fb3,
    const float* __restrict__ iW1, const float* __restrict__ ib1,
    const float* __restrict__ ib2, const float* __restrict__ iW3, const float* __restrict__ ib3,
    uint16_t* __restrict__ uT)
{
  __shared__ __align__(16) uint16_t W2l[128 * 136];
  __shared__ __align__(16) uint16_t hb[64 * 136];
  __shared__ float vls[256];
  __shared__ float sls[256 * 3];
  __shared__ float Ils[256];
  __shared__ float cW1[4 * 128];
  __shared__ float cb1[128];
  __shared__ float cb2[128];
  __shared__ float cW3[128 * 4];
  __shared__ float cb3[4];

  int t = threadIdx.x;
  int p0 = blockIdx.x * 256;
  int w = t >> 6, l = t & 63;

  {
    float v = 0.f;
    for (int ks = 0; ks < vparts; ++ks) v += vsrc[(size_t)ks * NB_ + p0 + t];
    vls[t] = v;
    for (int e = 0; e < 3; ++e) sls[e * 256 + t] = ssrc[(size_t)p0 * 3 + e * 256 + t];
    Ils[t] = Isrc[p0 + t];
  }

  for (int ph = 0; ph < 2; ++ph) {
    const uint16_t* W2g = ph ? W2iT : W2fT;
    const float* W1 = ph ? iW1 : fW1;
    const float* b1 = ph ? ib1 : fb1;
    const float* b2 = ph ? ib2 : fb2;
    const float* W3 = ph ? iW3 : fW3;
    const float* b3 = ph ? ib3 : fb3;
    int n_out = ph ? 1 : 3;
    __syncthreads();
    // stage W2^T [128][136]
    for (int e = 0; e < 32; ++e) {
      int idx = e * 256 + t;
      int r = idx >> 6, kp = idx & 63;
      ((uint32_t*)&W2l[r * 136])[kp] = ((const uint32_t*)W2g)[r * 64 + kp];
    }
    for (int i = t; i < 512; i += 256) cW1[i] = W1[i];
    if (t < 128) {
      cb1[t] = b1[t];
      cb2[t] = b2[t];
      for (int o = 0; o < n_out; ++o) cW3[t * 4 + o] = W3[t * n_out + o];
    }
    if (t < 4) cb3[t] = (t < n_out) ? b3[t] : 0.f;
    __syncthreads();

    for (int st = 0; st < 4; ++st) {
      int pb = st * 64;
      // layer 1 (VALU, fp32): thread = (point, quarter of 128 hidden)
      {
        int pr = t >> 2;
        int part = t & 3;
        int pl = pb + pr;
        float vn = (vls[pl] - VMEAN_) * (1.0f / VSTD_);
        float s0v = sls[pl * 3 + 0], s1v = sls[pl * 3 + 1], s2v = sls[pl * 3 + 2];
        int jbase = part * 32;
        for (int jj = 0; jj < 32; jj += 2) {
          int j = jbase + jj;
          float z0 = cb1[j]     + vn * cW1[j]     + s0v * cW1[128 + j]     + s1v * cW1[256 + j]     + s2v * cW1[384 + j];
          float z1 = cb1[j + 1] + vn * cW1[j + 1] + s0v * cW1[128 + j + 1] + s1v * cW1[256 + j + 1] + s2v * cW1[384 + j + 1];
          uint32_t pk = (uint32_t)f2bf(fast_tanh(z0)) | ((uint32_t)f2bf(fast_tanh(z1)) << 16);
          *(uint32_t*)&hb[pr * 136 + j] = pk;
        }
      }
      __syncthreads();
      // layer 2 (MFMA): wave w handles 16 points
      f32x4 acc[8];
      for (int ct = 0; ct < 8; ++ct) { f32x4 z = {0.f,0.f,0.f,0.f}; acc[ct] = z; }
      for (int ks = 0; ks < 4; ++ks) {
        bf16x8 a = *(const bf16x8*)&hb[(w * 16 + (l & 15)) * 136 + (l >> 4) * 8 + ks * 32];
        for (int ct = 0; ct < 8; ++ct) {
          bf16x8 b = *(const bf16x8*)&W2l[(ct * 16 + (l & 15)) * 136 + (l >> 4) * 8 + ks * 32];
          acc[ct] = mfma16(a, b, acc[ct]);
        }
      }
      // tanh + layer 3 (in-register, butterfly over 16-lane group)
      float fa[4][3];
      for (int e = 0; e < 4; ++e) for (int o = 0; o < 3; ++o) fa[e][o] = 0.f;
      for (int ct = 0; ct < 8; ++ct) {
        int j = ct * 16 + (l & 15);
        float bias = cb2[j];
        float w3v[3];
        for (int o = 0; o < n_out; ++o) w3v[o] = cW3[j * 4 + o];
        for (int e = 0; e < 4; ++e) {
          float h2 = fast_tanh(acc[ct][e] + bias);
          for (int o = 0; o < n_out; ++o) fa[e][o] += h2 * w3v[o];
        }
      }
      for (int m = 1; m < 16; m <<= 1)
        for (int e = 0; e < 4; ++e)
          for (int o = 0; o < n_out; ++o)
            fa[e][o] += __shfl_xor(fa[e][o], m, 64);
      if ((l & 15) == 0) {
        for (int e = 0; e < 4; ++e) {
          int pl = pb + w * 16 + (l >> 4) * 4 + e;
          int P = p0 + pl;
          if (ph == 0) {
            for (int o = 0; o < 3; ++o) {
              float snew = sls[pl * 3 + o] + DT_ * (fa[e][o] + cb3[o]);
              sls[pl * 3 + o] = snew;
              sdst[(size_t)P * 3 + o] = snew;
            }
          } else {
            float I_ion = (fa[e][0] + cb3[0]) * VSTD_ + VMEAN_;
            float u = vls[pl] + DT_ * Ils[pl] - DT_ * I_ion;
            int n = P >> 6, b = P & 63;
            uT[(size_t)b * 4096 + n] = f2bf(u);
          }
        }
      }
      __syncthreads();
    }
  }
}

// ---------------- per-step GEMM: partial[ks] = A_pre(ks-slice) @ u ----------------
__global__ __launch_bounds__(256) void k_gemm(const uint16_t* __restrict__ Apre,
                                              const uint16_t* __restrict__ uT,
                                              float* __restrict__ partial) {
  __shared__ __align__(16) uint16_t Al[64 * 72];
  __shared__ __align__(16) uint16_t Bl[64 * 72];
  int t = threadIdx.x, w = t >> 6, l = t & 63;
  int ksl = blockIdx.x & 7;
  int i0 = (blockIdx.x >> 3) * 64;
  f32x4 acc[4];
  for (int ct = 0; ct < 4; ++ct) { f32x4 z = {0.f,0.f,0.f,0.f}; acc[ct] = z; }
  for (int ch = 0; ch < 8; ++ch) {
    int k0 = ksl * 512 + ch * 64;
    __syncthreads();
    for (int it = 0; it < 2; ++it) {
      int s = it * 256 + t;
      int r = s >> 3, sl = s & 7;
      uint4 da = *(const uint4*)(Apre + (size_t)(i0 + r) * 4096 + k0 + sl * 8);
      *(uint4*)&Al[r * 72 + sl * 8] = da;
      uint4 db = *(const uint4*)(uT + (size_t)r * 4096 + k0 + sl * 8);
      *(uint4*)&Bl[r * 72 + sl * 8] = db;
    }
    __syncthreads();
    for (int ks = 0; ks < 2; ++ks) {
      bf16x8 a = *(const bf16x8*)&Al[(w * 16 + (l & 15)) * 72 + (l >> 4) * 8 + ks * 32];
      for (int ct = 0; ct < 4; ++ct) {
        bf16x8 b = *(const bf16x8*)&Bl[(ct * 16 + (l & 15)) * 72 + (l >> 4) * 8 + ks * 32];
        acc[ct] = mfma16(a, b, acc[ct]);
      }
    }
  }
  float* dst = partial + (size_t)ksl * NB_;
  for (int ct = 0; ct < 4; ++ct)
    for (int e = 0; e < 4; ++e) {
      int i = i0 + w * 16 + (l >> 4) * 4 + e;
      int b = ct * 16 + (l & 15);
      dst[(size_t)i * 64 + b] = acc[ct][e];
    }
}

// ---------------- final reduce: d_out = sum of 8 partials ----------------
__global__ void k_reduce(const float* __restrict__ partial, float* __restrict__ out) {
  int idx = (blockIdx.x * 256 + threadIdx.x) * 4;
  f32x4 s = {0.f, 0.f, 0.f, 0.f};
  for (int ks = 0; ks < 8; ++ks)
    s += *(const f32x4*)(partial + (size_t)ks * NB_ + idx);
  *(f32x4*)(out + idx) = s;
}

extern "C" void kernel_launch(void* const* d_in, const int* in_sizes, int n_in,
                              void* d_out, int out_size, void* d_ws, size_t ws_size,
                              hipStream_t stream) {
  const float* v0   = (const float*)d_in[0];
  const float* s0   = (const float*)d_in[1];
  const float* I_s  = (const float*)d_in[2];
  const float* mass = (const float*)d_in[3];
  const float* ipde = (const float*)d_in[4];
  const float* fW1 = (const float*)d_in[5];
  const float* fb1 = (const float*)d_in[6];
  const float* fW2 = (const float*)d_in[7];
  const float* fb2 = (const float*)d_in[8];
  const float* fW3 = (const float*)d_in[9];
  const float* fb3 = (const float*)d_in[10];
  const float* iW1 = (const float*)d_in[11];
  const float* ib1 = (const float*)d_in[12];
  const float* iW2 = (const float*)d_in[13];
  const float* ib2 = (const float*)d_in[14];
  const float* iW3 = (const float*)d_in[15];
  const float* ib3 = (const float*)d_in[16];

  char* ws = (char*)d_ws;
  uint16_t* Apre   = (uint16_t*)(ws);                 // 33,554,432 B
  uint16_t* W2fT   = (uint16_t*)(ws + 33554432);      // 32,768 B
  uint16_t* W2iT   = (uint16_t*)(ws + 33587200);      // 32,768 B
  float*    sstate = (float*)   (ws + 33619968);      // 3,145,728 B
  uint16_t* uT     = (uint16_t*)(ws + 36765696);      // 524,288 B
  float*    part   = (float*)   (ws + 37289984);      // 8,388,608 B  (total ~43.6 MB)

  k_prep_small<<<2, 256, 0, stream>>>(fW2, iW2, W2fT, W2iT);
  k_prep_gemm<<<1024, 256, 0, stream>>>(ipde, mass, Apre);
  for (int t = 0; t < T_; ++t) {
    const float* vsrc = (t == 0) ? v0 : part;
    int vparts = (t == 0) ? 1 : 8;
    const float* ssrc = (t == 0) ? s0 : sstate;
    k_mlp<<<NB_ / 256, 256, 0, stream>>>(vsrc, vparts, ssrc, sstate,
        I_s + (size_t)t * NB_, W2fT, W2iT,
        fW1, fb1, fb2, fW3, fb3, iW1, ib1, ib2, iW3, ib3, uT);
    k_gemm<<<512, 256, 0, stream>>>(Apre, uT, part);
  }
  k_reduce<<<256, 256, 0, stream>>>(part, (float*)d_out);
}

// Round 4
// 21744.064 us; speedup vs baseline: 1.1639x; 1.1639x over previous
//
#include <hip/hip_runtime.h>
#include <stdint.h>

#define N_     4096
#define B_     64
#define NB_    (N_*B_)      // 262144
#define T_     128
#define DT_    0.01f
#define VMEAN_ (-75.0f)
#define VSTD_  115.0f

typedef short bf16x8 __attribute__((ext_vector_type(8)));
typedef float f32x4  __attribute__((ext_vector_type(4)));

static __device__ __forceinline__ uint16_t f2bf(float f) {
  union { float f; uint32_t u; } v; v.f = f;
  uint32_t u = v.u;
  return (uint16_t)((u + 0x7FFFu + ((u >> 16) & 1u)) >> 16);  // RNE
}

static __device__ __forceinline__ float fast_tanh(float x) {
  // tanh(x) = 1 - 2/(exp2(x*2/ln2)+1); saturates cleanly for |x| large
  float ex = __builtin_amdgcn_exp2f(x * 2.8853900817779268f);
  return 1.0f - 2.0f * __builtin_amdgcn_rcpf(ex + 1.0f);
}

static __device__ __forceinline__ f32x4 mfma16(bf16x8 a, bf16x8 b, f32x4 c) {
  return __builtin_amdgcn_mfma_f32_16x16x32_bf16(a, b, c, 0, 0, 0);
}

// ---------------- prep: transpose 128x128 W2 matrices to bf16 [j][k] ----------------
__global__ void k_prep_small(const float* __restrict__ fW2, const float* __restrict__ iW2,
                             uint16_t* __restrict__ W2fT, uint16_t* __restrict__ W2iT) {
  const float* src = (blockIdx.x == 0) ? fW2 : iW2;
  uint16_t* dst = (blockIdx.x == 0) ? W2fT : W2iT;
  int t = threadIdx.x;
  for (int e = 0; e < 64; ++e) {
    int idx = e * 256 + t;           // idx = j*128 + k
    int j = idx >> 7, k = idx & 127;
    dst[idx] = f2bf(src[k * 128 + j]);
  }
}

// ---------------- prep: A_pre = inv_pde @ mass (bf16 out, fp32 in) ----------------
__global__ __launch_bounds__(256) void k_prep_gemm(const float* __restrict__ Ipde,
                                                   const float* __restrict__ Mmat,
                                                   uint16_t* __restrict__ Apre) {
  __shared__ __align__(16) uint16_t Al[128 * 72];
  __shared__ __align__(16) uint16_t Bl[128 * 72];
  int t = threadIdx.x;
  int row0 = (blockIdx.x >> 5) * 128;
  int col0 = (blockIdx.x & 31) * 128;
  int w = t >> 6, l = t & 63;
  int wr = (w >> 1) * 64, wc = (w & 1) * 64;
  f32x4 acc[4][4];
  for (int i = 0; i < 4; ++i)
    for (int j = 0; j < 4; ++j) { f32x4 z = {0.f,0.f,0.f,0.f}; acc[i][j] = z; }
  for (int ch = 0; ch < 64; ++ch) {
    int k0 = ch * 64;
    __syncthreads();
    for (int e = 0; e < 16; ++e) {
      int idx = e * 256 + t;
      int r = idx >> 5;
      int kp = (idx & 31) * 2;
      const float2 f2v = *(const float2*)(Ipde + (size_t)(row0 + r) * 4096 + k0 + kp);
      uint32_t pk = (uint32_t)f2bf(f2v.x) | ((uint32_t)f2bf(f2v.y) << 16);
      *(uint32_t*)&Al[r * 72 + kp] = pk;
    }
    for (int e = 0; e < 32; ++e) {
      int idx = e * 256 + t;
      int kk = idx >> 7, jj = idx & 127;
      Bl[jj * 72 + kk] = f2bf(Mmat[(size_t)(k0 + kk) * 4096 + col0 + jj]);
    }
    __syncthreads();
    for (int ks = 0; ks < 2; ++ks) {
      bf16x8 af[4], bfv[4];
      for (int rt = 0; rt < 4; ++rt)
        af[rt] = *(const bf16x8*)&Al[(wr + rt * 16 + (l & 15)) * 72 + (l >> 4) * 8 + ks * 32];
      for (int ct = 0; ct < 4; ++ct)
        bfv[ct] = *(const bf16x8*)&Bl[(wc + ct * 16 + (l & 15)) * 72 + (l >> 4) * 8 + ks * 32];
      for (int rt = 0; rt < 4; ++rt)
        for (int ct = 0; ct < 4; ++ct)
          acc[rt][ct] = mfma16(af[rt], bfv[ct], acc[rt][ct]);
    }
  }
  for (int rt = 0; rt < 4; ++rt)
    for (int ct = 0; ct < 4; ++ct)
      for (int e = 0; e < 4; ++e) {
        int i = row0 + wr + rt * 16 + (l >> 4) * 4 + e;
        int j = col0 + wc + ct * 16 + (l & 15);
        Apre[(size_t)i * 4096 + j] = f2bf(acc[rt][ct][e]);
      }
}

// ---------------- per-step fused MLP kernel (v2fix: reg-weights layer1, W2 in regs) ----------------
__global__ __launch_bounds__(256, 2) void k_mlp(
    const float* __restrict__ vsrc, int vparts,
    const float* __restrict__ ssrc, float* __restrict__ sdst,
    const float* __restrict__ Isrc,
    const uint16_t* __restrict__ W2fT, const uint16_t* __restrict__ W2iT,
    const float* __restrict__ fW1, const float* __restrict__ fb1,
    const float* __restrict__ fb2, const float* __restrict__ fW3, const float* __restrict__ fb3,
    const float* __restrict__ iW1, const float* __restrict__ ib1,
    const float* __restrict__ ib2, const float* __restrict__ iW3, const float* __restrict__ ib3,
    uint16_t* __restrict__ uT)
{
  __shared__ __align__(16) uint16_t hb[128 * 136];   // 34,816 B: half-tile (128 pts x 128 hidden)
  __shared__ __align__(16) float inp[256 * 4];       //  4,096 B: {vn, s0, s1, s2} per point
  __shared__ float vls[256];                         //  1,024 B
  __shared__ float Ils[256];                         //  1,024 B   (total ~41 KB)

  int t = threadIdx.x;
  int p0 = blockIdx.x * 256;
  int w = t >> 6, l = t & 63;
  int jp = t & 63;                 // layer1: hidden-pair index (j = 2*jp, 2*jp+1)
  int pg = t >> 6;                 // layer1: point-group (32 rows each)
  int lq = l >> 4, lr = l & 15;    // MFMA fragment coords

  {
    float v = 0.f;
    for (int ks = 0; ks < vparts; ++ks) v += vsrc[(size_t)ks * NB_ + p0 + t];
    vls[t] = v;
    Ils[t] = Isrc[p0 + t];
    inp[t * 4 + 0] = (v - VMEAN_) * (1.0f / VSTD_);
    for (int o = 0; o < 3; ++o) inp[t * 4 + 1 + o] = ssrc[(size_t)(p0 + t) * 3 + o];
  }
  __syncthreads();

  for (int ph = 0; ph < 2; ++ph) {
    const uint16_t* W2g = ph ? W2iT : W2fT;
    const float* W1 = ph ? iW1 : fW1;
    const float* b1 = ph ? ib1 : fb1;
    const float* b2 = ph ? ib2 : fb2;
    const float* W3 = ph ? iW3 : fW3;
    const float* b3 = ph ? ib3 : fb3;
    int n_out = ph ? 1 : 3;

    // per-phase register loads (small L2-hot tables)
    float w1r[2][5];
#pragma unroll
    for (int h = 0; h < 2; ++h) {
      int j = jp * 2 + h;
      w1r[h][0] = b1[j];
#pragma unroll
      for (int i = 0; i < 4; ++i) w1r[h][1 + i] = W1[i * 128 + j];
    }
    float cb2r[8], w3r[8][3], b3r[3];
#pragma unroll
    for (int ct = 0; ct < 8; ++ct) {
      int j = ct * 16 + lr;
      cb2r[ct] = b2[j];
      for (int o = 0; o < 3; ++o) w3r[ct][o] = (o < n_out) ? W3[j * n_out + o] : 0.f;
    }
    for (int o = 0; o < 3; ++o) b3r[o] = (o < n_out) ? b3[o] : 0.f;

    // W2^T fragments into registers (reused across all point-groups of both halves)
    bf16x8 bfr[4][8];
#pragma unroll
    for (int ks = 0; ks < 4; ++ks)
#pragma unroll
      for (int ct = 0; ct < 8; ++ct)
        bfr[ks][ct] = *(const bf16x8*)&W2g[(ct * 16 + lr) * 128 + lq * 8 + ks * 32];

    for (int hf = 0; hf < 2; ++hf) {
      // ---- layer 1: weights in regs; per row one broadcast b128 read, 64-lane-wide write ----
#pragma unroll 4
      for (int i = 0; i < 32; ++i) {
        int row = pg * 32 + i;
        int pt = hf * 128 + row;
        f32x4 xi = *(const f32x4*)&inp[pt * 4];
        float z0 = w1r[0][0] + xi.x * w1r[0][1] + xi.y * w1r[0][2] + xi.z * w1r[0][3] + xi.w * w1r[0][4];
        float z1 = w1r[1][0] + xi.x * w1r[1][1] + xi.y * w1r[1][2] + xi.z * w1r[1][3] + xi.w * w1r[1][4];
        uint32_t pk = (uint32_t)f2bf(fast_tanh(z0)) | ((uint32_t)f2bf(fast_tanh(z1)) << 16);
        ((uint32_t*)hb)[row * 68 + jp] = pk;
      }
      __syncthreads();
      // ---- layer 2 (MFMA) + tanh + layer 3 + epilogue, 2 point-groups per wave ----
#pragma unroll
      for (int gg = 0; gg < 2; ++gg) {
        int g = w * 2 + gg;
        f32x4 acc[8];
#pragma unroll
        for (int ct = 0; ct < 8; ++ct) { f32x4 z = {0.f,0.f,0.f,0.f}; acc[ct] = z; }
#pragma unroll
        for (int ks = 0; ks < 4; ++ks) {
          bf16x8 a = *(const bf16x8*)&hb[(g * 16 + lr) * 136 + lq * 8 + ks * 32];
#pragma unroll
          for (int ct = 0; ct < 8; ++ct)
            acc[ct] = mfma16(a, bfr[ks][ct], acc[ct]);
        }
        float fa[4][3];
#pragma unroll
        for (int e = 0; e < 4; ++e) for (int o = 0; o < 3; ++o) fa[e][o] = 0.f;
#pragma unroll
        for (int ct = 0; ct < 8; ++ct) {
#pragma unroll
          for (int e = 0; e < 4; ++e) {
            float h2 = fast_tanh(acc[ct][e] + cb2r[ct]);
            for (int o = 0; o < n_out; ++o) fa[e][o] += h2 * w3r[ct][o];
          }
        }
        for (int m = 1; m < 16; m <<= 1)
          for (int e = 0; e < 4; ++e)
            for (int o = 0; o < n_out; ++o)
              fa[e][o] += __shfl_xor(fa[e][o], m, 64);
        if (lr == 0) {
#pragma unroll
          for (int e = 0; e < 4; ++e) {
            int pl = hf * 128 + g * 16 + lq * 4 + e;
            int P = p0 + pl;
            if (ph == 0) {
              for (int o = 0; o < 3; ++o) {
                float snew = inp[pl * 4 + 1 + o] + DT_ * (fa[e][o] + b3r[o]);
                inp[pl * 4 + 1 + o] = snew;
                sdst[(size_t)P * 3 + o] = snew;
              }
            } else {
              float I_ion = (fa[e][0] + b3r[0]) * VSTD_ + VMEAN_;
              float u = vls[pl] + DT_ * Ils[pl] - DT_ * I_ion;
              uT[(size_t)(P & 63) * 4096 + (P >> 6)] = f2bf(u);
            }
          }
        }
      }
      __syncthreads();
    }
  }
}

// ---------------- per-step GEMM: partial[ks] = A_pre(ks-slice) @ u  (T14 prefetch) ----------------
__global__ __launch_bounds__(256) void k_gemm(const uint16_t* __restrict__ Apre,
                                              const uint16_t* __restrict__ uT,
                                              float* __restrict__ partial) {
  __shared__ __align__(16) uint16_t Al[64 * 72];
  __shared__ __align__(16) uint16_t Bl[64 * 72];
  int t = threadIdx.x, w = t >> 6, l = t & 63;
  int ksl = blockIdx.x & 7;
  int i0 = (blockIdx.x >> 3) * 64;
  int r0 = t >> 3, sl0 = t & 7;         // it=0 slot
  int r1 = 32 + (t >> 3), sl1 = t & 7;  // it=1 slot
  f32x4 acc[4];
  for (int ct = 0; ct < 4; ++ct) { f32x4 z = {0.f,0.f,0.f,0.f}; acc[ct] = z; }

  uint4 da0, da1, db0, db1;
  {
    int k0 = ksl * 512;
    da0 = *(const uint4*)(Apre + (size_t)(i0 + r0) * 4096 + k0 + sl0 * 8);
    db0 = *(const uint4*)(uT + (size_t)r0 * 4096 + k0 + sl0 * 8);
    da1 = *(const uint4*)(Apre + (size_t)(i0 + r1) * 4096 + k0 + sl1 * 8);
    db1 = *(const uint4*)(uT + (size_t)r1 * 4096 + k0 + sl1 * 8);
    *(uint4*)&Al[r0 * 72 + sl0 * 8] = da0;
    *(uint4*)&Bl[r0 * 72 + sl0 * 8] = db0;
    *(uint4*)&Al[r1 * 72 + sl1 * 8] = da1;
    *(uint4*)&Bl[r1 * 72 + sl1 * 8] = db1;
  }
  __syncthreads();

  for (int ch = 0; ch < 8; ++ch) {
    if (ch < 7) {  // issue next chunk's loads before computing current (T14)
      int k0 = ksl * 512 + (ch + 1) * 64;
      da0 = *(const uint4*)(Apre + (size_t)(i0 + r0) * 4096 + k0 + sl0 * 8);
      db0 = *(const uint4*)(uT + (size_t)r0 * 4096 + k0 + sl0 * 8);
      da1 = *(const uint4*)(Apre + (size_t)(i0 + r1) * 4096 + k0 + sl1 * 8);
      db1 = *(const uint4*)(uT + (size_t)r1 * 4096 + k0 + sl1 * 8);
    }
    for (int ks = 0; ks < 2; ++ks) {
      bf16x8 a = *(const bf16x8*)&Al[(w * 16 + (l & 15)) * 72 + (l >> 4) * 8 + ks * 32];
      for (int ct = 0; ct < 4; ++ct) {
        bf16x8 b = *(const bf16x8*)&Bl[(ct * 16 + (l & 15)) * 72 + (l >> 4) * 8 + ks * 32];
        acc[ct] = mfma16(a, b, acc[ct]);
      }
    }
    __syncthreads();
    if (ch < 7) {
      *(uint4*)&Al[r0 * 72 + sl0 * 8] = da0;
      *(uint4*)&Bl[r0 * 72 + sl0 * 8] = db0;
      *(uint4*)&Al[r1 * 72 + sl1 * 8] = da1;
      *(uint4*)&Bl[r1 * 72 + sl1 * 8] = db1;
      __syncthreads();
    }
  }
  float* dst = partial + (size_t)ksl * NB_;
  for (int ct = 0; ct < 4; ++ct)
    for (int e = 0; e < 4; ++e) {
      int i = i0 + w * 16 + (l >> 4) * 4 + e;
      int b = ct * 16 + (l & 15);
      dst[(size_t)i * 64 + b] = acc[ct][e];
    }
}

// ---------------- final reduce: d_out = sum of 8 partials ----------------
__global__ void k_reduce(const float* __restrict__ partial, float* __restrict__ out) {
  int idx = (blockIdx.x * 256 + threadIdx.x) * 4;
  f32x4 s = {0.f, 0.f, 0.f, 0.f};
  for (int ks = 0; ks < 8; ++ks)
    s += *(const f32x4*)(partial + (size_t)ks * NB_ + idx);
  *(f32x4*)(out + idx) = s;
}

extern "C" void kernel_launch(void* const* d_in, const int* in_sizes, int n_in,
                              void* d_out, int out_size, void* d_ws, size_t ws_size,
                              hipStream_t stream) {
  const float* v0   = (const float*)d_in[0];
  const float* s0   = (const float*)d_in[1];
  const float* I_s  = (const float*)d_in[2];
  const float* mass = (const float*)d_in[3];
  const float* ipde = (const float*)d_in[4];
  const float* fW1 = (const float*)d_in[5];
  const float* fb1 = (const float*)d_in[6];
  const float* fW2 = (const float*)d_in[7];
  const float* fb2 = (const float*)d_in[8];
  const float* fW3 = (const float*)d_in[9];
  const float* fb3 = (const float*)d_in[10];
  const float* iW1 = (const float*)d_in[11];
  const float* ib1 = (const float*)d_in[12];
  const float* iW2 = (const float*)d_in[13];
  const float* ib2 = (const float*)d_in[14];
  const float* iW3 = (const float*)d_in[15];
  const float* ib3 = (const float*)d_in[16];

  char* ws = (char*)d_ws;
  uint16_t* Apre   = (uint16_t*)(ws);                 // 33,554,432 B
  uint16_t* W2fT   = (uint16_t*)(ws + 33554432);      // 32,768 B
  uint16_t* W2iT   = (uint16_t*)(ws + 33587200);      // 32,768 B
  float*    sstate = (float*)   (ws + 33619968);      // 3,145,728 B
  uint16_t* uT     = (uint16_t*)(ws + 36765696);      // 524,288 B
  float*    part   = (float*)   (ws + 37289984);      // 8,388,608 B  (total ~43.6 MB)

  k_prep_small<<<2, 256, 0, stream>>>(fW2, iW2, W2fT, W2iT);
  k_prep_gemm<<<1024, 256, 0, stream>>>(ipde, mass, Apre);
  for (int t = 0; t < T_; ++t) {
    const float* vsrc = (t == 0) ? v0 : part;
    int vparts = (t == 0) ? 1 : 8;
    const float* ssrc = (t == 0) ? s0 : sstate;
    k_mlp<<<NB_ / 256, 256, 0, stream>>>(vsrc, vparts, ssrc, sstate,
        I_s + (size_t)t * NB_, W2fT, W2iT,
        fW1, fb1, fb2, fW3, fb3, iW1, ib1, ib2, iW3, ib3, uT);
    k_gemm<<<512, 256, 0, stream>>>(Apre, uT, part);
  }
  k_reduce<<<256, 256, 0, stream>>>(part, (float*)d_out);
}